// Round 11
// baseline (1077.451 us; speedup 1.0000x reference)
//
#include <hip/hip_runtime.h>

#define N_NODES 50000
#define NE 1000000
#define NBUK 391     // buckets of 128 consecutive dst nodes: ceil(50000/128)
#define CHUNK 4096   // edges per bucket_scatter/count block
#define CB 245       // ceil(NE/CHUNK)
#define CONVB 3125   // conv blocks: 50000*64/4/256

typedef float vfloat4 __attribute__((ext_vector_type(4)));
typedef unsigned short ushort4v __attribute__((ext_vector_type(4)));
typedef unsigned short ushort8v __attribute__((ext_vector_type(8)));

__device__ __forceinline__ unsigned short f2b(float f) {  // RNE f32->bf16
  unsigned u = __float_as_uint(f);
  u += 0x7FFF + ((u >> 16) & 1);
  return (unsigned short)(u >> 16);
}
__device__ __forceinline__ float b2f(unsigned short h) {
  return __uint_as_float(((unsigned)h) << 16);
}

// ws layout (4-byte units), end 6,451,536 = 25.8 MB (< 29 MB proven safe):
//   XB   [N*64 bf] @ 0          (x-bf16, then h-bf16 after layer1)
//   AE   [N*16]f   @ 1,600,000
//   DEG  [N]       @ 2,400,000
//   BCNT [512]     @ 2,450,000
//   BCUR [512]     @ 2,450,512
//   BOFF [512]     @ 2,451,024
//   BKT  [E ll]    @ 2,451,536  (byte 9,806,144: 8B aligned)
// AGG lives in d_out (scratch until layer2's final in-place overwrite).
// payload pack (44 bits): [eid:20 | src:17 | dst&127:7]

// fused: blocks [0,CB) count dst buckets; blocks [CB,CB+CONVB) convert x->bf16
__global__ __launch_bounds__(256) void prologue_kernel(
    const float* __restrict__ x, const int* __restrict__ ei,
    int* __restrict__ BCNT, unsigned short* __restrict__ XB) {
  int b = blockIdx.x;
  int t = threadIdx.x;
  if (b < CB) {
    __shared__ int c[512];
    c[t] = 0; c[t + 256] = 0;
    __syncthreads();
    int i0 = b * CHUNK;
    int n = min(CHUNK, NE - i0);
    for (int i = t; i < n; i += 256)
      atomicAdd(&c[ei[NE + i0 + i] >> 7], 1);
    __syncthreads();
    for (int bb = t; bb < NBUK; bb += 256)
      if (c[bb] > 0) atomicAdd(&BCNT[bb], c[bb]);
  } else {
    int i = (b - CB) * 256 + t;
    if (i < (N_NODES * 64) / 4) {
      vfloat4 v = ((const vfloat4*)x)[i];
      ushort4v o = { f2b(v[0]), f2b(v[1]), f2b(v[2]), f2b(v[3]) };
      ((ushort4v*)XB)[i] = o;
    }
  }
}

// single block: exclusive scan of BCNT -> BOFF, BCUR
__global__ __launch_bounds__(512) void scan_buckets(
    const int* __restrict__ BCNT, int* __restrict__ BOFF, int* __restrict__ BCUR) {
  __shared__ int s[512];
  int t = threadIdx.x;
  int v = (t < NBUK) ? BCNT[t] : 0;
  s[t] = v;
  __syncthreads();
  #pragma unroll
  for (int off = 1; off < 512; off <<= 1) {
    int u = (t >= off) ? s[t - off] : 0;
    __syncthreads();
    s[t] += u;
    __syncthreads();
  }
  int ex = s[t] - v;
  if (t < NBUK) { BOFF[t] = ex; BCUR[t] = ex; }
  if (t == NBUK - 1) BOFF[NBUK] = s[t];  // = NE
}

// bin edges into NBUK contiguous-dst-range buckets; LDS-staged contiguous
// run writes (one ~CHUNK/NBUK-edge run per (block,bucket)).
__global__ __launch_bounds__(512) void bucket_scatter(
    const int* __restrict__ ei, int* __restrict__ BCUR,
    long long* __restrict__ BKT) {
  __shared__ int cnt[512], sscan[512], base[512], cur[512], gb[512];
  __shared__ long long binned[CHUNK];
  __shared__ unsigned short dstl[CHUNK];
  int t = threadIdx.x;
  int c0 = blockIdx.x * CHUNK;
  int n = min(CHUNK, NE - c0);
  cnt[t] = 0;
  __syncthreads();
  for (int i = t; i < n; i += 512)
    atomicAdd(&cnt[ei[NE + c0 + i] >> 7], 1);
  __syncthreads();
  int myc = cnt[t];
  sscan[t] = myc;
  __syncthreads();
  #pragma unroll
  for (int off = 1; off < 512; off <<= 1) {
    int u = (t >= off) ? sscan[t - off] : 0;
    __syncthreads();
    sscan[t] += u;
    __syncthreads();
  }
  base[t] = sscan[t] - myc;
  cur[t] = base[t];
  if (myc > 0) gb[t] = atomicAdd(&BCUR[t], myc);
  __syncthreads();
  for (int i = t; i < n; i += 512) {
    int src = ei[c0 + i];
    int dst = ei[NE + c0 + i];
    int b = dst >> 7;
    int lp = atomicAdd(&cur[b], 1);
    binned[lp] = ((long long)(c0 + i) << 24) | ((long long)src << 7)
               | (long long)(dst & 127);
    dstl[lp] = (unsigned short)dst;
  }
  __syncthreads();
  for (int i = t; i < n; i += 512) {
    int b = ((int)dstl[i]) >> 7;
    BKT[gb[b] + (i - base[b])] = binned[i];
  }
}

// Fused sort+gather: one block per bucket (128 dst nodes). Stream the
// bucket's contiguous BKT run; per edge read the full 128B bf16 row
// (8 lanes x 16B, one cache line); accumulate into an LDS f32 accumulator
// (stride 68 spreads rows across banks); coalesced write-out + DEG.
template <bool HAS_EA>
__global__ __launch_bounds__(1024) void bucket_gather(
    const unsigned short* __restrict__ XB,  // [N,64] bf16
    const float* __restrict__ ea,           // [E,16] or null
    const long long* __restrict__ BKT, const int* __restrict__ BOFF,
    float* __restrict__ AGG,                // [N,64] (d_out scratch)
    float* __restrict__ AEout,              // [N,16] or null
    int* __restrict__ DEG)                  // [N] or null
{
  __shared__ float acc[128][68];
  __shared__ float aeacc[128][20];
  __shared__ int cnt[128];
  int t = threadIdx.x;
  int b = blockIdx.x;
  for (int i = t; i < 128 * 68; i += 1024) ((float*)acc)[i] = 0.f;
  if (HAS_EA) {
    for (int i = t; i < 128 * 20; i += 1024) ((float*)aeacc)[i] = 0.f;
    if (t < 128) cnt[t] = 0;
  }
  __syncthreads();
  int s0 = BOFF[b], s1 = BOFF[b + 1];
  int n = s1 - s0;
  int slot = t >> 3;  // 0..127: edge slot
  int j = t & 7;      // 16B chunk within the 128B row
  for (int i = slot; i < n; i += 128) {
    long long pl = BKT[s0 + i];
    int dl = (int)(pl & 127);
    int src = (int)((pl >> 7) & 0x1FFFF);
    ushort8v v = ((const ushort8v*)XB)[src * 8 + j];
    #pragma unroll
    for (int k = 0; k < 8; ++k) atomicAdd(&acc[dl][j * 8 + k], b2f(v[k]));
    if (HAS_EA) {
      if (j < 4) {
        int eid = (int)(pl >> 24);
        vfloat4 ev = *(const vfloat4*)(ea + eid * 16 + j * 4);
        #pragma unroll
        for (int k = 0; k < 4; ++k) atomicAdd(&aeacc[dl][j * 4 + k], ev[k]);
      }
      if (j == 7) atomicAdd(&cnt[dl], 1);
    }
  }
  __syncthreads();
  int nb0 = b << 7;
  for (int i = t; i < 128 * 16; i += 1024) {
    int r = i >> 4, c = i & 15;
    if (nb0 + r < N_NODES) {
      vfloat4 o = *(const vfloat4*)&acc[r][c * 4];
      ((vfloat4*)AGG)[(nb0 + r) * 16 + c] = o;
    }
  }
  if (HAS_EA) {
    for (int i = t; i < 128 * 4; i += 1024) {
      int r = i >> 2, c = i & 3;
      if (nb0 + r < N_NODES) {
        vfloat4 o = *(const vfloat4*)&aeacc[r][c * 4];
        ((vfloat4*)AEout)[(nb0 + r) * 4 + c] = o;
      }
    }
    if (t < 128 && nb0 + t < N_NODES) DEG[nb0 + t] = cnt[t];
  }
}

// out[i][:] = relu( x@Ws + bs + bn + ((AGG+x)@Wn_top + AE@Wn_bot)/(deg+1) )
// XBF: xin is bf16. OBF: out is bf16. In-place on AGG safe: block stages its
// own 64 rows into LDS before writing exactly those rows.
template <bool XBF, bool OBF>
__global__ __launch_bounds__(256) void layer_kernel(
    const void* __restrict__ xin_, const float* __restrict__ AGG,
    const float* __restrict__ AE, const int* __restrict__ DEG,
    const float* __restrict__ Ws, const float* __restrict__ bs,
    const float* __restrict__ Wn, const float* __restrict__ bn,
    void* __restrict__ out_)
{
  __shared__ float Ml[144][68];
  __shared__ float Wl[72][64];
  __shared__ float biasl[64];
  __shared__ float invl[64];

  const float* xf = (const float*)xin_;
  const unsigned short* xb = (const unsigned short*)xin_;

  int t = threadIdx.x;
  int base = blockIdx.x * 64;

  if (t < 64) {
    int i = base + t;
    float deg = (i < N_NODES) ? (float)DEG[i] : 0.0f;
    invl[t] = 1.0f / (deg + 1.0f);
    biasl[t] = bs[t] + bn[t];
  }
  __syncthreads();

  for (int idx = t; idx < 4096; idx += 256) {
    int r = idx >> 6, k = idx & 63;
    int i = base + r;
    float xv = 0.f, av = 0.f;
    if (i < N_NODES) {
      xv = XBF ? b2f(xb[i * 64 + k]) : xf[i * 64 + k];
      av = AGG[i * 64 + k];
    }
    Ml[k][r] = xv;
    Ml[64 + k][r] = (av + xv) * invl[r];
  }
  for (int idx = t; idx < 1024; idx += 256) {
    int r = idx >> 4, k = idx & 15;
    int i = base + r;
    Ml[128 + k][r] = (i < N_NODES) ? AE[i * 16 + k] * invl[r] : 0.0f;
  }

  int tx = t & 15;
  int ty = t >> 4;
  float acc[4][4] = {{0.f}};

  for (int kc = 0; kc < 2; ++kc) {
    for (int idx = t; idx < 72 * 64; idx += 256) {
      int lr = idx >> 6, c = idx & 63;
      int k = kc * 72 + lr;
      Wl[lr][c] = (k < 64) ? Ws[k * 64 + c] : Wn[(k - 64) * 64 + c];
    }
    __syncthreads();
    #pragma unroll 8
    for (int k = 0; k < 72; ++k) {
      float4 a = *(const float4*)&Ml[kc * 72 + k][ty * 4];
      float4 b = *(const float4*)&Wl[k][tx * 4];
      float av[4] = {a.x, a.y, a.z, a.w};
      float bv[4] = {b.x, b.y, b.z, b.w};
      #pragma unroll
      for (int ri = 0; ri < 4; ++ri)
        #pragma unroll
        for (int ci = 0; ci < 4; ++ci)
          acc[ri][ci] = fmaf(av[ri], bv[ci], acc[ri][ci]);
    }
    __syncthreads();
  }

  #pragma unroll
  for (int ri = 0; ri < 4; ++ri) {
    int i = base + ty * 4 + ri;
    if (i < N_NODES) {
      float o0 = fmaxf(acc[ri][0] + biasl[tx * 4 + 0], 0.0f);
      float o1 = fmaxf(acc[ri][1] + biasl[tx * 4 + 1], 0.0f);
      float o2 = fmaxf(acc[ri][2] + biasl[tx * 4 + 2], 0.0f);
      float o3 = fmaxf(acc[ri][3] + biasl[tx * 4 + 3], 0.0f);
      if (OBF) {
        ushort4v ob = { f2b(o0), f2b(o1), f2b(o2), f2b(o3) };
        ((ushort4v*)out_)[i * 16 + tx] = ob;
      } else {
        float4 of = {o0, o1, o2, o3};
        ((float4*)out_)[i * 16 + tx] = of;
      }
    }
  }
}

extern "C" void kernel_launch(void* const* d_in, const int* in_sizes, int n_in,
                              void* d_out, int out_size, void* d_ws, size_t ws_size,
                              hipStream_t stream) {
  const float* x   = (const float*)d_in[0];
  const int*   ei  = (const int*)d_in[1];
  const float* ea  = (const float*)d_in[2];
  const float* W1n = (const float*)d_in[3];
  const float* b1n = (const float*)d_in[4];
  const float* W1s = (const float*)d_in[5];
  const float* b1s = (const float*)d_in[6];
  const float* W2n = (const float*)d_in[7];
  const float* b2n = (const float*)d_in[8];
  const float* W2s = (const float*)d_in[9];
  const float* b2s = (const float*)d_in[10];

  int* wsi = (int*)d_ws;
  float* wsf = (float*)d_ws;
  unsigned short* XB = (unsigned short*)wsi;          // [0, 1,600,000)
  float* AE  = wsf + 1600000;                         // 3.2 MB
  int*  DEG  = wsi + 2400000;
  int*  BCNT = wsi + 2450000;
  int*  BCUR = wsi + 2450512;
  int*  BOFF = wsi + 2451024;
  long long* BKT = (long long*)(wsi + 2451536);       // 8 MB
  float* AGG = (float*)d_out;                         // scratch until layer2
  float* out = (float*)d_out;

  hipMemsetAsync(BCNT, 0, 512 * 4, stream);

  prologue_kernel<<<CB + CONVB, 256, 0, stream>>>(x, ei, BCNT, XB);
  scan_buckets<<<1, 512, 0, stream>>>(BCNT, BOFF, BCUR);
  bucket_scatter<<<CB, 512, 0, stream>>>(ei, BCUR, BKT);

  bucket_gather<true><<<NBUK, 1024, 0, stream>>>(XB, ea, BKT, BOFF, AGG, AE, DEG);
  layer_kernel<false, true><<<782, 256, 0, stream>>>(
      x, AGG, AE, DEG, W1s, b1s, W1n, b1n, XB);   // h (bf16) overwrites XB
  bucket_gather<false><<<NBUK, 1024, 0, stream>>>(XB, nullptr, BKT, BOFF, AGG, nullptr, nullptr);
  layer_kernel<true, false><<<782, 256, 0, stream>>>(
      XB, AGG, AE, DEG, W2s, b2s, W2n, b2n, out); // in-place on d_out
}

// Round 12
// 246.776 us; speedup vs baseline: 4.3661x; 4.3661x over previous
//
#include <hip/hip_runtime.h>

#define N_NODES 50000
#define NE 1000000
#define NBUK 196     // buckets of 256 consecutive dst nodes
#define CHUNK 4096   // edges per bucket_scatter/count block
#define MAXBE 6144   // LDS edge-buffer capacity in bucket_sort

typedef float vfloat4 __attribute__((ext_vector_type(4)));
typedef unsigned short ushort4v __attribute__((ext_vector_type(4)));
typedef unsigned short ushort8v __attribute__((ext_vector_type(8)));

__device__ __forceinline__ unsigned short f2b(float f) {  // RNE f32->bf16
  unsigned u = __float_as_uint(f);
  u += 0x7FFF + ((u >> 16) & 1);
  return (unsigned short)(u >> 16);
}
__device__ __forceinline__ float b2f(unsigned short h) {
  return __uint_as_float(((unsigned)h) << 16);
}

// ws layout (4-byte units), end 6,500,772 = 26.0 MB (< 29 MB proven safe):
//   OFF   [N+1]     @ 0
//   OFFH  [N]       @ 50004     (src-half boundary within each node's run)
//   SRT   [E ll]    @ 100004    (byte 400016, 8B aligned)
//   XB    [N*64 bf] @ 2100004   (x-bf16, then h-bf16 after layer1)
//   AE    [N*16]f   @ 3700004
//   BCNT  [256]     @ 4500004
//   BOFF  [256]     @ 4500260
//   BCUR  [256]     @ 4500516
//   BKT   [E ll]    @ 4500772   (byte 18003088, 8B aligned)
// AGG lives in d_out (scratch until layer2's final in-place overwrite).
// payload pack (45 bits): [eid:20 | src:17 | dst&255:8]

__global__ __launch_bounds__(256) void bucket_count(
    const int* __restrict__ ei, int* __restrict__ BCNT) {
  __shared__ int c[256];
  int t = threadIdx.x;
  c[t] = 0;
  __syncthreads();
  int i0 = blockIdx.x * CHUNK;
  int n = min(CHUNK, NE - i0);
  for (int i = t; i < n; i += 256)
    atomicAdd(&c[ei[NE + i0 + i] >> 8], 1);
  __syncthreads();
  if (t < NBUK && c[t] > 0) atomicAdd(&BCNT[t], c[t]);
}

__global__ __launch_bounds__(256) void scan_buckets(
    const int* __restrict__ BCNT, int* __restrict__ BOFF,
    int* __restrict__ BCUR, int* __restrict__ OFF) {
  __shared__ int s[256];
  int t = threadIdx.x;
  int v = (t < NBUK) ? BCNT[t] : 0;
  s[t] = v;
  __syncthreads();
  #pragma unroll
  for (int off = 1; off < 256; off <<= 1) {
    int u = (t >= off) ? s[t - off] : 0;
    __syncthreads();
    s[t] += u;
    __syncthreads();
  }
  int ex = s[t] - v;
  if (t < NBUK) { BOFF[t] = ex; BCUR[t] = ex; }
  if (t == NBUK - 1) BOFF[NBUK] = s[t];  // = NE
  if (t == 0) OFF[N_NODES] = NE;
}

__global__ __launch_bounds__(256) void bucket_scatter(
    const int* __restrict__ ei, int* __restrict__ BCUR,
    long long* __restrict__ BKT) {
  __shared__ int cnt[256], sscan[256], base[256], cur[256], gb[256];
  __shared__ long long binned[CHUNK];
  __shared__ unsigned short dstl[CHUNK];
  int t = threadIdx.x;
  int c0 = blockIdx.x * CHUNK;
  int n = min(CHUNK, NE - c0);
  cnt[t] = 0;
  __syncthreads();
  for (int i = t; i < n; i += 256) {
    int dst = ei[NE + c0 + i];
    atomicAdd(&cnt[dst >> 8], 1);
  }
  __syncthreads();
  int myc = cnt[t];
  sscan[t] = myc;
  __syncthreads();
  #pragma unroll
  for (int off = 1; off < 256; off <<= 1) {
    int u = (t >= off) ? sscan[t - off] : 0;
    __syncthreads();
    sscan[t] += u;
    __syncthreads();
  }
  base[t] = sscan[t] - myc;
  cur[t] = sscan[t] - myc;
  if (myc > 0) gb[t] = atomicAdd(&BCUR[t], myc);
  __syncthreads();
  for (int i = t; i < n; i += 256) {
    int src = ei[c0 + i];
    int dst = ei[NE + c0 + i];
    int b = dst >> 8;
    int lp = atomicAdd(&cur[b], 1);
    binned[lp] = ((long long)(c0 + i) << 25) | ((long long)src << 8)
               | (long long)(dst & 255);
    dstl[lp] = (unsigned short)dst;
  }
  __syncthreads();
  for (int i = t; i < n; i += 256) {
    int b = ((int)dstl[i]) >> 8;
    __builtin_nontemporal_store(binned[i], &BKT[gb[b] + (i - base[b])]);
  }
}

// One block per bucket. Per-dst counts split by src-half; local scan -> OFF
// and OFFH (half boundary); place into SRT: half0 edges first, then half1.
__global__ __launch_bounds__(1024) void bucket_sort(
    const long long* __restrict__ BKT, const int* __restrict__ BOFF,
    int* __restrict__ OFF, int* __restrict__ OFFH, long long* __restrict__ SRT) {
  __shared__ int cnt0[256], cnt1[256], ss[256], loff[256], cur0[256], cur1[256];
  __shared__ long long buf[MAXBE];
  int t = threadIdx.x;
  if (t < 256) { cnt0[t] = 0; cnt1[t] = 0; cur0[t] = 0; cur1[t] = 0; }
  __syncthreads();
  int b = blockIdx.x;
  int s0 = BOFF[b], s1 = BOFF[b + 1];
  int n = s1 - s0;
  for (int i = t; i < n; i += 1024) {
    long long pl = __builtin_nontemporal_load(&BKT[s0 + i]);
    if (i < MAXBE) buf[i] = pl;
    int dl = (int)(pl & 255);
    int src = (int)((pl >> 8) & 0x1FFFF);
    if (src < N_NODES / 2) atomicAdd(&cnt0[dl], 1);
    else                   atomicAdd(&cnt1[dl], 1);
  }
  __syncthreads();
  if (t < 256) ss[t] = cnt0[t] + cnt1[t];
  __syncthreads();
  #pragma unroll
  for (int off = 1; off < 256; off <<= 1) {
    int u = 0;
    if (t < 256 && t >= off) u = ss[t - off];
    __syncthreads();
    if (t < 256) ss[t] += u;
    __syncthreads();
  }
  if (t < 256) loff[t] = ss[t] - (cnt0[t] + cnt1[t]);
  __syncthreads();
  int nb0 = b << 8;
  if (t < 256 && nb0 + t < N_NODES) {
    OFF[nb0 + t] = s0 + loff[t];
    OFFH[nb0 + t] = s0 + loff[t] + cnt0[t];
  }
  for (int i = t; i < n; i += 1024) {
    long long pl = (i < MAXBE) ? buf[i] : __builtin_nontemporal_load(&BKT[s0 + i]);
    int dl = (int)(pl & 255);
    int src = (int)((pl >> 8) & 0x1FFFF);
    int pos;
    if (src < N_NODES / 2) pos = s0 + loff[dl] + atomicAdd(&cur0[dl], 1);
    else                   pos = s0 + loff[dl] + cnt0[dl] + atomicAdd(&cur1[dl], 1);
    SRT[pos] = pl;
  }
}

__global__ __launch_bounds__(256) void conv_bf16(
    const float* __restrict__ in, unsigned short* __restrict__ out) {
  int i = blockIdx.x * 256 + threadIdx.x;  // one float4 per thread
  if (i >= (N_NODES * 64) / 4) return;
  vfloat4 v = ((const vfloat4*)in)[i];
  ushort4v o = { f2b(v[0]), f2b(v[1]), f2b(v[2]), f2b(v[3]) };
  ((ushort4v*)out)[i] = o;
}

// One wave per node; 8 edge-slots x 8 lanes; lane reads ushort8 (16B) of the
// bf16 row (128B = 1 line/edge). HALF selects the src-range sublist
// [OFF,OFFH) or [OFFH,OFF+1): per-dispatch random working set = 25k rows
// = 3.2 MB < 4 MB per-XCD L2 by construction. HALF=1 accumulates into AGG/AE.
template <bool HAS_EA, int HALF>
__global__ __launch_bounds__(256) void gather_agg(
    const unsigned short* __restrict__ XB,  // [N,64] bf16
    const float* __restrict__ ea,           // [E,16] or null
    const long long* __restrict__ SRT, const int* __restrict__ OFF,
    const int* __restrict__ OFFH,
    float* __restrict__ AGG,                // [N,64] (d_out scratch)
    float* __restrict__ AEout)              // [N,16] or null
{
  int w = (blockIdx.x * 256 + threadIdx.x) >> 6;
  int lane = threadIdx.x & 63;
  if (w >= N_NODES) return;
  int s0 = HALF ? OFFH[w] : OFF[w];
  int s1 = HALF ? OFF[w + 1] : OFFH[w];
  int slot = lane >> 3;   // 0..7
  int j = lane & 7;       // ushort8 chunk within row
  float ax[8] = {0.f,0.f,0.f,0.f,0.f,0.f,0.f,0.f};
  float ae0=0.f, ae1=0.f, ae2=0.f, ae3=0.f;
  for (int p = s0 + slot; p < s1; p += 8) {
    long long pl = __builtin_nontemporal_load(&SRT[p]);
    int src = (int)((pl >> 8) & 0x1FFFF);
    ushort8v v = ((const ushort8v*)XB)[src * 8 + j];
    #pragma unroll
    for (int k = 0; k < 8; ++k) ax[k] += b2f(v[k]);
    if (HAS_EA) {
      int eid = (int)(pl >> 25);
      if (j < 4) {
        vfloat4 ev = __builtin_nontemporal_load((const vfloat4*)(ea + eid * 16 + j * 4));
        ae0 += ev[0]; ae1 += ev[1]; ae2 += ev[2]; ae3 += ev[3];
      }
    }
  }
  #pragma unroll
  for (int m = 8; m <= 32; m <<= 1) {
    #pragma unroll
    for (int k = 0; k < 8; ++k) ax[k] += __shfl_xor(ax[k], m, 64);
    if (HAS_EA) {
      ae0 += __shfl_xor(ae0, m, 64);
      ae1 += __shfl_xor(ae1, m, 64);
      ae2 += __shfl_xor(ae2, m, 64);
      ae3 += __shfl_xor(ae3, m, 64);
    }
  }
  if (lane < 8) {
    vfloat4 o0 = {ax[0], ax[1], ax[2], ax[3]};
    vfloat4 o1 = {ax[4], ax[5], ax[6], ax[7]};
    if (HALF) {
      vfloat4 p0 = *(const vfloat4*)(AGG + w * 64 + lane * 8);
      vfloat4 p1 = *(const vfloat4*)(AGG + w * 64 + lane * 8 + 4);
      o0 += p0; o1 += p1;
    }
    __builtin_nontemporal_store(o0, (vfloat4*)(AGG + w * 64 + lane * 8));
    __builtin_nontemporal_store(o1, (vfloat4*)(AGG + w * 64 + lane * 8 + 4));
  }
  if (HAS_EA && lane < 4) {
    vfloat4 oe = {ae0, ae1, ae2, ae3};
    if (HALF) {
      vfloat4 pe = *(const vfloat4*)(AEout + w * 16 + lane * 4);
      oe += pe;
    }
    __builtin_nontemporal_store(oe, (vfloat4*)(AEout + w * 16 + lane * 4));
  }
}

// out[i][:] = relu( x@Ws + bs + bn + ((AGG+x)@Wn_top + AE@Wn_bot)/(deg+1) )
// XBF: xin is bf16. OBF: out is bf16. In-place on AGG safe: block stages its
// own 64 rows into LDS before writing exactly those rows.
template <bool XBF, bool OBF>
__global__ __launch_bounds__(256) void layer_kernel(
    const void* __restrict__ xin_, const float* __restrict__ AGG,
    const float* __restrict__ AE, const int* __restrict__ OFF,
    const float* __restrict__ Ws, const float* __restrict__ bs,
    const float* __restrict__ Wn, const float* __restrict__ bn,
    void* __restrict__ out_)
{
  __shared__ float Ml[144][68];
  __shared__ float Wl[72][64];
  __shared__ float biasl[64];
  __shared__ float invl[64];

  const float* xf = (const float*)xin_;
  const unsigned short* xb = (const unsigned short*)xin_;

  int t = threadIdx.x;
  int base = blockIdx.x * 64;

  if (t < 64) {
    int i = base + t;
    float deg = (i < N_NODES) ? (float)(OFF[i + 1] - OFF[i]) : 0.0f;
    invl[t] = 1.0f / (deg + 1.0f);
    biasl[t] = bs[t] + bn[t];
  }
  __syncthreads();

  for (int idx = t; idx < 4096; idx += 256) {
    int r = idx >> 6, k = idx & 63;
    int i = base + r;
    float xv = 0.f, av = 0.f;
    if (i < N_NODES) {
      xv = XBF ? b2f(xb[i * 64 + k]) : xf[i * 64 + k];
      av = AGG[i * 64 + k];
    }
    Ml[k][r] = xv;
    Ml[64 + k][r] = (av + xv) * invl[r];
  }
  for (int idx = t; idx < 1024; idx += 256) {
    int r = idx >> 4, k = idx & 15;
    int i = base + r;
    Ml[128 + k][r] = (i < N_NODES) ? AE[i * 16 + k] * invl[r] : 0.0f;
  }

  int tx = t & 15;
  int ty = t >> 4;
  float acc[4][4] = {{0.f}};

  for (int kc = 0; kc < 2; ++kc) {
    for (int idx = t; idx < 72 * 64; idx += 256) {
      int lr = idx >> 6, c = idx & 63;
      int k = kc * 72 + lr;
      Wl[lr][c] = (k < 64) ? Ws[k * 64 + c] : Wn[(k - 64) * 64 + c];
    }
    __syncthreads();
    #pragma unroll 8
    for (int k = 0; k < 72; ++k) {
      float4 a = *(const float4*)&Ml[kc * 72 + k][ty * 4];
      float4 b = *(const float4*)&Wl[k][tx * 4];
      float av[4] = {a.x, a.y, a.z, a.w};
      float bv[4] = {b.x, b.y, b.z, b.w};
      #pragma unroll
      for (int ri = 0; ri < 4; ++ri)
        #pragma unroll
        for (int ci = 0; ci < 4; ++ci)
          acc[ri][ci] = fmaf(av[ri], bv[ci], acc[ri][ci]);
    }
    __syncthreads();
  }

  #pragma unroll
  for (int ri = 0; ri < 4; ++ri) {
    int i = base + ty * 4 + ri;
    if (i < N_NODES) {
      float o0 = fmaxf(acc[ri][0] + biasl[tx * 4 + 0], 0.0f);
      float o1 = fmaxf(acc[ri][1] + biasl[tx * 4 + 1], 0.0f);
      float o2 = fmaxf(acc[ri][2] + biasl[tx * 4 + 2], 0.0f);
      float o3 = fmaxf(acc[ri][3] + biasl[tx * 4 + 3], 0.0f);
      if (OBF) {
        ushort4v ob = { f2b(o0), f2b(o1), f2b(o2), f2b(o3) };
        ((ushort4v*)out_)[i * 16 + tx] = ob;
      } else {
        float4 of = {o0, o1, o2, o3};
        ((float4*)out_)[i * 16 + tx] = of;
      }
    }
  }
}

extern "C" void kernel_launch(void* const* d_in, const int* in_sizes, int n_in,
                              void* d_out, int out_size, void* d_ws, size_t ws_size,
                              hipStream_t stream) {
  const float* x   = (const float*)d_in[0];
  const int*   ei  = (const int*)d_in[1];
  const float* ea  = (const float*)d_in[2];
  const float* W1n = (const float*)d_in[3];
  const float* b1n = (const float*)d_in[4];
  const float* W1s = (const float*)d_in[5];
  const float* b1s = (const float*)d_in[6];
  const float* W2n = (const float*)d_in[7];
  const float* b2n = (const float*)d_in[8];
  const float* W2s = (const float*)d_in[9];
  const float* b2s = (const float*)d_in[10];

  int* wsi = (int*)d_ws;
  float* wsf = (float*)d_ws;
  int*  OFF  = wsi;                                   // [0, 50001)
  int*  OFFH = wsi + 50004;                           // [50004, 100004)
  long long* SRT = (long long*)(wsi + 100004);        // 8 MB
  unsigned short* XB = (unsigned short*)(wsi + 2100004);  // 6.4 MB bf16
  float* AE  = wsf + 3700004;                         // 3.2 MB
  int*  BCNT = wsi + 4500004;
  int*  BOFF = wsi + 4500260;
  int*  BCUR = wsi + 4500516;
  long long* BKT = (long long*)(wsi + 4500772);       // 8 MB
  float* AGG = (float*)d_out;                         // scratch until layer2
  float* out = (float*)d_out;

  hipMemsetAsync(BCNT, 0, 256 * 4, stream);

  int cb = (NE + CHUNK - 1) / CHUNK;  // 245
  bucket_count<<<cb, 256, 0, stream>>>(ei, BCNT);
  scan_buckets<<<1, 256, 0, stream>>>(BCNT, BOFF, BCUR, OFF);
  bucket_scatter<<<cb, 256, 0, stream>>>(ei, BCUR, BKT);
  bucket_sort<<<NBUK, 1024, 0, stream>>>(BKT, BOFF, OFF, OFFH, SRT);
  conv_bf16<<<(N_NODES * 64 / 4 + 255) / 256, 256, 0, stream>>>(x, XB);

  gather_agg<true, 0><<<12500, 256, 0, stream>>>(XB, ea, SRT, OFF, OFFH, AGG, AE);
  gather_agg<true, 1><<<12500, 256, 0, stream>>>(XB, ea, SRT, OFF, OFFH, AGG, AE);
  layer_kernel<false, true><<<782, 256, 0, stream>>>(
      x, AGG, AE, OFF, W1s, b1s, W1n, b1n, XB);   // h (bf16) overwrites XB
  gather_agg<false, 0><<<12500, 256, 0, stream>>>(XB, nullptr, SRT, OFF, OFFH, AGG, nullptr);
  gather_agg<false, 1><<<12500, 256, 0, stream>>>(XB, nullptr, SRT, OFF, OFFH, AGG, nullptr);
  layer_kernel<true, false><<<782, 256, 0, stream>>>(
      XB, AGG, AE, OFF, W2s, b2s, W2n, b2n, out); // in-place on d_out
}

// Round 13
// 215.027 us; speedup vs baseline: 5.0108x; 1.1476x over previous
//
#include <hip/hip_runtime.h>

#define N_NODES 50000
#define NE 1000000
#define NBUK 196     // buckets of 256 consecutive dst nodes
#define CHUNK 4096   // edges per bucket_scatter/count block
#define CB 245       // ceil(NE/CHUNK)
#define MAXBE 6144   // LDS edge-buffer capacity in bucket_sort
#define CONVB 3125   // conv sub-blocks: 50000*64/4/256

typedef float vfloat4 __attribute__((ext_vector_type(4)));
typedef unsigned short ushort4v __attribute__((ext_vector_type(4)));
typedef unsigned short ushort8v __attribute__((ext_vector_type(8)));

__device__ __forceinline__ unsigned short f2b(float f) {  // RNE f32->bf16
  unsigned u = __float_as_uint(f);
  u += 0x7FFF + ((u >> 16) & 1);
  return (unsigned short)(u >> 16);
}
__device__ __forceinline__ float b2f(unsigned short h) {
  return __uint_as_float(((unsigned)h) << 16);
}

// ws layout (4-byte units), end 6,450,772 = 25.8 MB (< 29 MB proven safe):
//   OFF   [N+1]     @ 0
//   SRT   [E ll]    @ 50004     (byte 200016, 8B aligned)
//   XB    [N*64 bf] @ 2050004   (x-bf16, then h-bf16 after layer1)
//   AE    [N*16]f   @ 3650004
//   BCNT  [256]     @ 4450004
//   BOFF  [256]     @ 4450260
//   BCUR  [256]     @ 4450516
//   BKT   [E ll]    @ 4450772
// AGG lives in d_out (scratch until layer2's final in-place overwrite).
// payload pack (45 bits): [eid:20 | src:17 | dst&255:8]

// fused (proven in R10): blocks [0,CB) count dst buckets; [CB,CB+CONVB) x->bf16
__global__ __launch_bounds__(256) void prologue_kernel(
    const float* __restrict__ x, const int* __restrict__ ei,
    int* __restrict__ BCNT, unsigned short* __restrict__ XB) {
  int b = blockIdx.x;
  int t = threadIdx.x;
  if (b < CB) {
    __shared__ int c[256];
    c[t] = 0;
    __syncthreads();
    int i0 = b * CHUNK;
    int n = min(CHUNK, NE - i0);
    for (int i = t; i < n; i += 256)
      atomicAdd(&c[ei[NE + i0 + i] >> 8], 1);
    __syncthreads();
    if (t < NBUK && c[t] > 0) atomicAdd(&BCNT[t], c[t]);
  } else {
    int i = (b - CB) * 256 + t;
    if (i < (N_NODES * 64) / 4) {
      vfloat4 v = ((const vfloat4*)x)[i];
      ushort4v o = { f2b(v[0]), f2b(v[1]), f2b(v[2]), f2b(v[3]) };
      ((ushort4v*)XB)[i] = o;
    }
  }
}

__global__ __launch_bounds__(256) void scan_buckets(
    const int* __restrict__ BCNT, int* __restrict__ BOFF,
    int* __restrict__ BCUR, int* __restrict__ OFF) {
  __shared__ int s[256];
  int t = threadIdx.x;
  int v = (t < NBUK) ? BCNT[t] : 0;
  s[t] = v;
  __syncthreads();
  #pragma unroll
  for (int off = 1; off < 256; off <<= 1) {
    int u = (t >= off) ? s[t - off] : 0;
    __syncthreads();
    s[t] += u;
    __syncthreads();
  }
  int ex = s[t] - v;
  if (t < NBUK) { BOFF[t] = ex; BCUR[t] = ex; }
  if (t == NBUK - 1) BOFF[NBUK] = s[t];  // = NE
  if (t == 0) OFF[N_NODES] = NE;
}

__global__ __launch_bounds__(256) void bucket_scatter(
    const int* __restrict__ ei, int* __restrict__ BCUR,
    long long* __restrict__ BKT) {
  __shared__ int cnt[256], sscan[256], base[256], cur[256], gb[256];
  __shared__ long long binned[CHUNK];
  __shared__ unsigned short dstl[CHUNK];
  int t = threadIdx.x;
  int c0 = blockIdx.x * CHUNK;
  int n = min(CHUNK, NE - c0);
  cnt[t] = 0;
  __syncthreads();
  for (int i = t; i < n; i += 256)
    atomicAdd(&cnt[ei[NE + c0 + i] >> 8], 1);
  __syncthreads();
  int myc = cnt[t];
  sscan[t] = myc;
  __syncthreads();
  #pragma unroll
  for (int off = 1; off < 256; off <<= 1) {
    int u = (t >= off) ? sscan[t - off] : 0;
    __syncthreads();
    sscan[t] += u;
    __syncthreads();
  }
  base[t] = sscan[t] - myc;
  cur[t] = sscan[t] - myc;
  if (myc > 0) gb[t] = atomicAdd(&BCUR[t], myc);
  __syncthreads();
  for (int i = t; i < n; i += 256) {
    int src = ei[c0 + i];
    int dst = ei[NE + c0 + i];
    int b = dst >> 8;
    int lp = atomicAdd(&cur[b], 1);
    binned[lp] = ((long long)(c0 + i) << 25) | ((long long)src << 8)
               | (long long)(dst & 255);
    dstl[lp] = (unsigned short)dst;
  }
  __syncthreads();
  for (int i = t; i < n; i += 256) {
    int b = ((int)dstl[i]) >> 8;
    __builtin_nontemporal_store(binned[i], &BKT[gb[b] + (i - base[b])]);
  }
}

__global__ __launch_bounds__(1024) void bucket_sort(
    const long long* __restrict__ BKT, const int* __restrict__ BOFF,
    int* __restrict__ OFF, long long* __restrict__ SRT) {
  __shared__ int cnt[256], ss[256], loff[256], cur[256];
  __shared__ long long buf[MAXBE];
  int t = threadIdx.x;
  int b = blockIdx.x;
  if (t < 256) { cnt[t] = 0; cur[t] = 0; }
  __syncthreads();
  int s0 = BOFF[b], s1 = BOFF[b + 1];
  int n = s1 - s0;
  for (int i = t; i < n; i += 1024) {
    long long pl = __builtin_nontemporal_load(&BKT[s0 + i]);
    if (i < MAXBE) buf[i] = pl;
    atomicAdd(&cnt[(int)(pl & 255)], 1);
  }
  __syncthreads();
  if (t < 256) ss[t] = cnt[t];
  __syncthreads();
  #pragma unroll
  for (int off = 1; off < 256; off <<= 1) {
    int u = 0;
    if (t < 256 && t >= off) u = ss[t - off];
    __syncthreads();
    if (t < 256) ss[t] += u;
    __syncthreads();
  }
  if (t < 256) loff[t] = ss[t] - cnt[t];
  __syncthreads();
  int nb0 = b << 8;
  if (t < 256 && nb0 + t < N_NODES) OFF[nb0 + t] = s0 + loff[t];
  for (int i = t; i < n; i += 1024) {
    long long pl = (i < MAXBE) ? buf[i] : __builtin_nontemporal_load(&BKT[s0 + i]);
    int dl = (int)(pl & 255);
    int p = atomicAdd(&cur[dl], 1);
    SRT[s0 + loff[dl] + p] = pl;
  }
}

// One wave per node; 8 edge-slots x 8 lanes; lane reads ushort8 (16B) of the
// bf16 row (128B = 1 cache line/edge — the byte floor). Streams NT.
template <bool HAS_EA>
__global__ __launch_bounds__(256) void gather_agg(
    const unsigned short* __restrict__ XB,  // [N,64] bf16
    const float* __restrict__ ea,           // [E,16] or null
    const long long* __restrict__ SRT, const int* __restrict__ OFF,
    float* __restrict__ AGG,                // [N,64] (d_out scratch)
    float* __restrict__ AEout)              // [N,16] or null
{
  int w = (blockIdx.x * 256 + threadIdx.x) >> 6;
  int lane = threadIdx.x & 63;
  if (w >= N_NODES) return;
  int s0 = OFF[w], s1 = OFF[w + 1];
  int slot = lane >> 3;   // 0..7
  int j = lane & 7;       // ushort8 chunk within row
  float ax[8] = {0.f,0.f,0.f,0.f,0.f,0.f,0.f,0.f};
  float ae0=0.f, ae1=0.f, ae2=0.f, ae3=0.f;
  for (int p = s0 + slot; p < s1; p += 8) {
    long long pl = __builtin_nontemporal_load(&SRT[p]);
    int src = (int)((pl >> 8) & 0x1FFFF);
    ushort8v v = ((const ushort8v*)XB)[src * 8 + j];
    #pragma unroll
    for (int k = 0; k < 8; ++k) ax[k] += b2f(v[k]);
    if (HAS_EA) {
      int eid = (int)(pl >> 25);
      if (j < 4) {
        vfloat4 ev = __builtin_nontemporal_load((const vfloat4*)(ea + eid * 16 + j * 4));
        ae0 += ev[0]; ae1 += ev[1]; ae2 += ev[2]; ae3 += ev[3];
      }
    }
  }
  #pragma unroll
  for (int m = 8; m <= 32; m <<= 1) {
    #pragma unroll
    for (int k = 0; k < 8; ++k) ax[k] += __shfl_xor(ax[k], m, 64);
    if (HAS_EA) {
      ae0 += __shfl_xor(ae0, m, 64);
      ae1 += __shfl_xor(ae1, m, 64);
      ae2 += __shfl_xor(ae2, m, 64);
      ae3 += __shfl_xor(ae3, m, 64);
    }
  }
  if (lane < 8) {
    vfloat4 o0 = {ax[0], ax[1], ax[2], ax[3]};
    vfloat4 o1 = {ax[4], ax[5], ax[6], ax[7]};
    __builtin_nontemporal_store(o0, (vfloat4*)(AGG + w * 64 + lane * 8));
    __builtin_nontemporal_store(o1, (vfloat4*)(AGG + w * 64 + lane * 8 + 4));
  }
  if (HAS_EA && lane < 4) {
    vfloat4 oe = {ae0, ae1, ae2, ae3};
    __builtin_nontemporal_store(oe, (vfloat4*)(AEout + w * 16 + lane * 4));
  }
}

// out[i][:] = relu( x@Ws + bs + bn + ((AGG+x)@Wn_top + AE@Wn_bot)/(deg+1) )
// XBF: xin is bf16. OBF: out is bf16. In-place on AGG safe: block stages its
// own 64 rows into LDS before writing exactly those rows.
template <bool XBF, bool OBF>
__global__ __launch_bounds__(256) void layer_kernel(
    const void* __restrict__ xin_, const float* __restrict__ AGG,
    const float* __restrict__ AE, const int* __restrict__ OFF,
    const float* __restrict__ Ws, const float* __restrict__ bs,
    const float* __restrict__ Wn, const float* __restrict__ bn,
    void* __restrict__ out_)
{
  __shared__ float Ml[144][68];
  __shared__ float Wl[72][64];
  __shared__ float biasl[64];
  __shared__ float invl[64];

  const float* xf = (const float*)xin_;
  const unsigned short* xb = (const unsigned short*)xin_;

  int t = threadIdx.x;
  int base = blockIdx.x * 64;

  if (t < 64) {
    int i = base + t;
    float deg = (i < N_NODES) ? (float)(OFF[i + 1] - OFF[i]) : 0.0f;
    invl[t] = 1.0f / (deg + 1.0f);
    biasl[t] = bs[t] + bn[t];
  }
  __syncthreads();

  for (int idx = t; idx < 4096; idx += 256) {
    int r = idx >> 6, k = idx & 63;
    int i = base + r;
    float xv = 0.f, av = 0.f;
    if (i < N_NODES) {
      xv = XBF ? b2f(xb[i * 64 + k]) : xf[i * 64 + k];
      av = AGG[i * 64 + k];
    }
    Ml[k][r] = xv;
    Ml[64 + k][r] = (av + xv) * invl[r];
  }
  for (int idx = t; idx < 1024; idx += 256) {
    int r = idx >> 4, k = idx & 15;
    int i = base + r;
    Ml[128 + k][r] = (i < N_NODES) ? AE[i * 16 + k] * invl[r] : 0.0f;
  }

  int tx = t & 15;
  int ty = t >> 4;
  float acc[4][4] = {{0.f}};

  for (int kc = 0; kc < 2; ++kc) {
    for (int idx = t; idx < 72 * 64; idx += 256) {
      int lr = idx >> 6, c = idx & 63;
      int k = kc * 72 + lr;
      Wl[lr][c] = (k < 64) ? Ws[k * 64 + c] : Wn[(k - 64) * 64 + c];
    }
    __syncthreads();
    #pragma unroll 8
    for (int k = 0; k < 72; ++k) {
      float4 a = *(const float4*)&Ml[kc * 72 + k][ty * 4];
      float4 b = *(const float4*)&Wl[k][tx * 4];
      float av[4] = {a.x, a.y, a.z, a.w};
      float bv[4] = {b.x, b.y, b.z, b.w};
      #pragma unroll
      for (int ri = 0; ri < 4; ++ri)
        #pragma unroll
        for (int ci = 0; ci < 4; ++ci)
          acc[ri][ci] = fmaf(av[ri], bv[ci], acc[ri][ci]);
    }
    __syncthreads();
  }

  #pragma unroll
  for (int ri = 0; ri < 4; ++ri) {
    int i = base + ty * 4 + ri;
    if (i < N_NODES) {
      float o0 = fmaxf(acc[ri][0] + biasl[tx * 4 + 0], 0.0f);
      float o1 = fmaxf(acc[ri][1] + biasl[tx * 4 + 1], 0.0f);
      float o2 = fmaxf(acc[ri][2] + biasl[tx * 4 + 2], 0.0f);
      float o3 = fmaxf(acc[ri][3] + biasl[tx * 4 + 3], 0.0f);
      if (OBF) {
        ushort4v ob = { f2b(o0), f2b(o1), f2b(o2), f2b(o3) };
        ((ushort4v*)out_)[i * 16 + tx] = ob;
      } else {
        float4 of = {o0, o1, o2, o3};
        ((float4*)out_)[i * 16 + tx] = of;
      }
    }
  }
}

extern "C" void kernel_launch(void* const* d_in, const int* in_sizes, int n_in,
                              void* d_out, int out_size, void* d_ws, size_t ws_size,
                              hipStream_t stream) {
  const float* x   = (const float*)d_in[0];
  const int*   ei  = (const int*)d_in[1];
  const float* ea  = (const float*)d_in[2];
  const float* W1n = (const float*)d_in[3];
  const float* b1n = (const float*)d_in[4];
  const float* W1s = (const float*)d_in[5];
  const float* b1s = (const float*)d_in[6];
  const float* W2n = (const float*)d_in[7];
  const float* b2n = (const float*)d_in[8];
  const float* W2s = (const float*)d_in[9];
  const float* b2s = (const float*)d_in[10];

  int* wsi = (int*)d_ws;
  float* wsf = (float*)d_ws;
  int*  OFF  = wsi;                                   // [0, 50001)
  long long* SRT = (long long*)(wsi + 50004);         // 8 MB
  unsigned short* XB = (unsigned short*)(wsi + 2050004);  // 6.4 MB bf16
  float* AE  = wsf + 3650004;                         // 3.2 MB
  int*  BCNT = wsi + 4450004;
  int*  BOFF = wsi + 4450260;
  int*  BCUR = wsi + 4450516;
  long long* BKT = (long long*)(wsi + 4450772);       // 8 MB
  float* AGG = (float*)d_out;                         // scratch until layer2
  float* out = (float*)d_out;

  hipMemsetAsync(BCNT, 0, 256 * 4, stream);

  prologue_kernel<<<CB + CONVB, 256, 0, stream>>>(x, ei, BCNT, XB);
  scan_buckets<<<1, 256, 0, stream>>>(BCNT, BOFF, BCUR, OFF);
  bucket_scatter<<<CB, 256, 0, stream>>>(ei, BCUR, BKT);
  bucket_sort<<<NBUK, 1024, 0, stream>>>(BKT, BOFF, OFF, SRT);

  gather_agg<true><<<12500, 256, 0, stream>>>(XB, ea, SRT, OFF, AGG, AE);
  layer_kernel<false, true><<<782, 256, 0, stream>>>(
      x, AGG, AE, OFF, W1s, b1s, W1n, b1n, XB);   // h (bf16) overwrites XB
  gather_agg<false><<<12500, 256, 0, stream>>>(XB, nullptr, SRT, OFF, AGG, nullptr);
  layer_kernel<true, false><<<782, 256, 0, stream>>>(
      XB, AGG, AE, OFF, W2s, b2s, W2n, b2n, out); // in-place on d_out
}